// Round 11
// baseline (224.250 us; speedup 1.0000x reference)
//
#include <hip/hip_runtime.h>
#include <hip/hip_bf16.h>

// z[b,c,m] = sum_d S[m,c,d] * (x[b,d,m] - mean[d,m])
// B=1024, C=64, M=512. x:(B,C,M) f32, mean:(1,C,M), S:(M,C,C), out f32.
//
// v9: v6 body (A-frags in regs once/block, mean folded into staging, reg-held
// depth-2 prefetch) resized for 2 blocks/CU: 1024 thr (16 waves, 1 m/wave,
// MT=16), BT=16, NB=4, grid 512. LDS 72 KB: x single 32 KB + z half 40 KB.
// 4 lgkm-only barriers/iter (vmcnt never drained). All LDS phases bank-floor.

typedef __attribute__((ext_vector_type(8))) short short8;
typedef __attribute__((ext_vector_type(4))) float f32x4;

namespace {
constexpr int Mm = 512, Cc = 64, Bb = 1024;
constexpr int MT = 16, BT = 16, NB = 4;
constexpr int ZP = 20;  // z row pitch (16 m + 4 pad), 16B-aligned
constexpr size_t LDSB = 32768 + 512 * ZP * 4;  // 73728 B

__device__ __forceinline__ short bfc(float f) {  // f32 -> bf16 RNE (HW cvt)
  __hip_bfloat16 h = __float2bfloat16(f);
  union { __hip_bfloat16 b; short s; } u;
  u.b = h;
  return u.s;
}
__device__ __forceinline__ unsigned pack2(float a, float b) {
  return (unsigned)(unsigned short)bfc(a) |
         ((unsigned)(unsigned short)bfc(b) << 16);
}
// x-LDS chunk swizzle (v6, conflict-audited): read rows vary in l&15,
// write rows vary in mq (row bit 6+).
__device__ __forceinline__ int xsw(int row, int c) {
  return c ^ (row & 7) ^ (((row >> 6) & 3) << 1);
}
}  // namespace

#define ELEM(V, I) ((I) == 0 ? (V).x : (I) == 1 ? (V).y : (I) == 2 ? (V).z : (V).w)

__global__ __launch_bounds__(1024, 8) void zca_v9(
    const float* __restrict__ x, const float* __restrict__ mean,
    const float* __restrict__ S, float* __restrict__ out) {
  extern __shared__ unsigned char lds[];
  unsigned char* xl = lds;            // 32 KB bf16 x-tile [row=m*16+b][64 d]
  float* zl = (float*)(lds + 32768);  // 40 KB z half-tile [512 rows][ZP]

  const int tid = threadIdx.x;
  const int l = tid & 63;
  const int w = __builtin_amdgcn_readfirstlane(tid >> 6);  // 0..15 = m_local

  // bijective XCD swizzle: 512 blocks; per XCD 4 m-tiles x 16 b-groups
  const int xcd = blockIdx.x & 7, ord = blockIdx.x >> 3;
  const int m0 = (xcd * 4 + (ord & 3)) * MT;
  const int b0 = (ord >> 2) * (BT * NB);

  // staging coords (v6 map): thread covers (d2,d2+1) x {bq, 8+bq} x 4 m
  const int mq = tid & 3;
  const int u = (tid >> 2) & 15;
  const int bq = w >> 1;
  const int d2 = ((w & 1) << 5) + (u << 1);
  const int chunkS = ((w & 1) << 2) + (u >> 2);
  // z-read coords: thread t -> row t&511, m-half qp = t>>9
  const int zrow_r = tid & 511;
  const int qp = tid >> 9;
  const int h2r = (tid >> 6) & 3;  // == (zrow_r>>6)&3, wave-uniform

  float4 st0[4], st1[4];

#define ISSUE(ST, T)                                                          \
  {                                                                           \
    _Pragma("unroll") for (int dd = 0; dd < 2; ++dd)                          \
        _Pragma("unroll") for (int p = 0; p < 2; ++p)                         \
            ST[dd * 2 + p] = *(const float4*)(                                \
                x + (size_t)((b0 + (T)*BT + p * 8 + bq) * Cc + d2 + dd) * Mm  \
                  + m0 + mq * 4);                                             \
  }

#define STAGE(ST)                                                             \
  {                                                                           \
    _Pragma("unroll") for (int p = 0; p < 2; ++p) {                           \
      _Pragma("unroll") for (int i = 0; i < 4; ++i) {                         \
        const int row = (mq * 4 + i) * BT + p * 8 + bq;                       \
        const unsigned v = pack2(ELEM(ST[p], i) - ELEM(mvE, i),               \
                                 ELEM(ST[2 + p], i) - ELEM(mvO, i));          \
        *(unsigned*)(xl + row * 128 + xsw(row, chunkS) * 16 + (u & 3) * 4) =  \
            v;                                                                \
      }                                                                       \
    }                                                                         \
  }

#define BAR()                                          \
  {                                                    \
    asm volatile("s_waitcnt lgkmcnt(0)" ::: "memory"); \
    __builtin_amdgcn_s_barrier();                      \
  }

  // z-write: c half H; col = w ^ (h2<<2) (quad-pure XOR, <=2-way banks)
#define ZW(H)                                                                 \
  {                                                                           \
    _Pragma("unroll") for (int c2 = 0; c2 < 2; ++c2) {                        \
      _Pragma("unroll") for (int r = 0; r < 4; ++r) {                         \
        const int h2 = l >> 4;                                                \
        const int zrow = (c2 * 16 + h2 * 4 + r) * 16 + (l & 15);              \
        zl[zrow * ZP + (w ^ (h2 << 2))] = acc[(H)*2 + c2][r];                 \
      }                                                                       \
    }                                                                         \
  }

  // z-read + store: quad q holds m-quad q ^ h2r (no intra-quad perm)
#define ZR(H, T)                                                              \
  {                                                                           \
    const int bz = zrow_r & 15, cl = (H)*32 + (zrow_r >> 4);                  \
    float* op = out + (size_t)((b0 + (T)*BT + bz) * Cc + cl) * Mm + m0;       \
    const float4 v0 = *(const float4*)(zl + zrow_r * ZP + (qp * 2) * 4);      \
    const float4 v1 = *(const float4*)(zl + zrow_r * ZP + (qp * 2 + 1) * 4);  \
    *(float4*)(op + ((qp * 2) ^ h2r) * 4) = v0;                               \
    *(float4*)(op + ((qp * 2 + 1) ^ h2r) * 4) = v1;                           \
  }

  // ---- prologue ----
  ISSUE(st0, 0)
  ISSUE(st1, 1)
  const float4 mvE = *(const float4*)(mean + (size_t)d2 * Mm + m0 + mq * 4);
  const float4 mvO =
      *(const float4*)(mean + (size_t)(d2 + 1) * Mm + m0 + mq * 4);

  short8 A[4][2];
#pragma unroll
  for (int ct = 0; ct < 4; ++ct) {
#pragma unroll
    for (int ks = 0; ks < 2; ++ks) {
      const float* sp = S + ((size_t)(m0 + w) * Cc + ct * 16 + (l & 15)) * Cc +
                        ks * 32 + (l >> 4) * 8;
      const float4 f0 = *(const float4*)sp;
      const float4 f1 = *(const float4*)(sp + 4);
      short8 a;
      a[0] = bfc(f0.x); a[1] = bfc(f0.y); a[2] = bfc(f0.z); a[3] = bfc(f0.w);
      a[4] = bfc(f1.x); a[5] = bfc(f1.y); a[6] = bfc(f1.z); a[7] = bfc(f1.w);
      A[ct][ks] = a;
    }
  }
  STAGE(st0)
  BAR()

#define ITER(T, STC, STN)                                                      \
  {                                                                            \
    const int rowB = w * BT + (l & 15);                                        \
    const short8 Bf0 = *(const short8*)(                                       \
        xl + rowB * 128 + xsw(rowB, (l >> 4)) * 16);                           \
    const short8 Bf1 = *(const short8*)(                                       \
        xl + rowB * 128 + xsw(rowB, 4 + (l >> 4)) * 16);                       \
    if ((T) + 2 < NB) ISSUE(STN, (T) + 2)                                      \
    f32x4 acc[4];                                                              \
    _Pragma("unroll") for (int ct = 0; ct < 4; ++ct) acc[ct] =                 \
        (f32x4){0.f, 0.f, 0.f, 0.f};                                           \
    _Pragma("unroll") for (int ct = 0; ct < 4; ++ct) acc[ct] =                 \
        __builtin_amdgcn_mfma_f32_16x16x32_bf16(A[ct][0], Bf0, acc[ct], 0, 0,  \
                                                0);                            \
    _Pragma("unroll") for (int ct = 0; ct < 4; ++ct) acc[ct] =                 \
        __builtin_amdgcn_mfma_f32_16x16x32_bf16(A[ct][1], Bf1, acc[ct], 0, 0,  \
                                                0);                            \
    BAR() /* 1: Bf reads + prev z-reads done */                                \
    if ((T) + 1 < NB) STAGE(STC)                                               \
    ZW(0)                                                                      \
    BAR() /* 2: stage + zw(h0) visible */                                      \
    ZR(0, T)                                                                   \
    BAR() /* 3: zr(h0) done */                                                 \
    ZW(1)                                                                      \
    BAR() /* 4: zw(h1) visible */                                              \
    ZR(1, T)                                                                   \
  }

  ITER(0, st1, st0)
  ITER(1, st0, st1)
  ITER(2, st1, st0)
  ITER(3, st0, st1)

#undef ITER
#undef ZR
#undef ZW
#undef BAR
#undef STAGE
#undef ISSUE
}

extern "C" void kernel_launch(void* const* d_in, const int* in_sizes, int n_in,
                              void* d_out, int out_size, void* d_ws,
                              size_t ws_size, hipStream_t stream) {
  const float* x = (const float*)d_in[0];
  const float* mean = (const float*)d_in[1];
  const float* S = (const float*)d_in[2];
  float* out = (float*)d_out;
  const int nblocks = (Mm / MT) * (Bb / (BT * NB));  // 32 * 16 = 512
  hipLaunchKernelGGL(zca_v9, dim3(nblocks), dim3(1024), LDSB, stream, x, mean,
                     S, out);
}

// Round 12
// 73.679 us; speedup vs baseline: 3.0436x; 3.0436x over previous
//
#include <hip/hip_runtime.h>
#include <hip/hip_bf16.h>

// z[b,c,m] = sum_d S[m,c,d] * (x[b,d,m] - mean[d,m])
// B=1024, C=64, M=512. x:(B,C,M) f32, mean:(1,C,M), S:(M,C,C), out f32.
//
// v10: round-6 structure (1024 thr, 16 waves, 1 m/wave, BT=16, NB=8, grid 256,
// A-frags in regs once/block, reg-held depth-2 prefetch, x LDS double-buffer,
// 2 lgkm-only barriers/iter) + NEW conflict-free z-path:
//   z LDS [m][ct][h][vcol][b] with vcol = (r ^ h ^ (m>>2)) & 3.
//   ZW 2-way free; ZR (4x b32 per float4-over-m) 2-way free; stores full-line.

typedef __attribute__((ext_vector_type(8))) short short8;
typedef __attribute__((ext_vector_type(4))) float f32x4;

namespace {
constexpr int Mm = 512, Cc = 64, Bb = 1024;
constexpr int MT = 16, BT = 16, NB = 8;
constexpr size_t LDSB = 65536 + 65536;  // x dbuf 2x32 KB + z 64 KB = 128 KB

__device__ __forceinline__ short bfc(float f) {  // f32 -> bf16 RNE (HW cvt)
  __hip_bfloat16 h = __float2bfloat16(f);
  union { __hip_bfloat16 b; short s; } u;
  u.b = h;
  return u.s;
}
__device__ __forceinline__ unsigned pack2(float a, float b) {
  return (unsigned)(unsigned short)bfc(a) |
         ((unsigned)(unsigned short)bfc(b) << 16);
}
// x-LDS chunk swizzle (v6, audited 2-way max on both sides)
__device__ __forceinline__ int xsw(int row, int c) {
  return c ^ (row & 7) ^ (((row >> 6) & 3) << 1);
}
}  // namespace

#define ELEM(V, I) ((I) == 0 ? (V).x : (I) == 1 ? (V).y : (I) == 2 ? (V).z : (V).w)

__global__ __launch_bounds__(1024, 4) void zca_v10(
    const float* __restrict__ x, const float* __restrict__ mean,
    const float* __restrict__ S, float* __restrict__ out) {
  extern __shared__ unsigned char lds[];
  unsigned char* xb0 = lds;            // 32 KB bf16 x tile, buffer 0
  unsigned char* xb1 = lds + 32768;    // 32 KB buffer 1
  float* zl = (float*)(lds + 65536);   // 64 KB z tile [16 m][1024]

  const int tid = threadIdx.x;
  const int l = tid & 63;
  const int w = __builtin_amdgcn_readfirstlane(tid >> 6);  // 0..15 = m_local

  // bijective XCD swizzle: 256 blocks; per XCD 4 m-tiles x 8 b-groups
  const int id = blockIdx.x;
  const int sw = ((id & 7) << 5) + (id >> 3);
  const int m0 = (sw >> 3) * MT;
  const int b0 = (sw & 7) * (BT * NB);

  // staging coords (v6): thread covers (d2,d2+1) x {bq, 8+bq} x 4 m
  const int mq = tid & 3;
  const int u = (tid >> 2) & 15;
  const int bq = w >> 1;
  const int d2 = ((w & 1) << 5) + (u << 1);
  const int chunkS = ((w & 1) << 2) + (u >> 2);
  // z-read coords: quad lanes = 4 m-quads of same (c,b)
  const int mqr = tid & 3;
  const int br = (tid >> 2) & 15;
  const int clow = (tid >> 6) & 15;  // == w

  float4 st0[4], st1[4];

#define ISSUE(ST, T)                                                          \
  {                                                                           \
    _Pragma("unroll") for (int dd = 0; dd < 2; ++dd)                          \
        _Pragma("unroll") for (int p = 0; p < 2; ++p)                         \
            ST[dd * 2 + p] = *(const float4*)(                                \
                x + (size_t)((b0 + (T)*BT + p * 8 + bq) * Cc + d2 + dd) * Mm  \
                  + m0 + mq * 4);                                             \
  }

#define STAGE(ST, XW)                                                         \
  {                                                                           \
    _Pragma("unroll") for (int p = 0; p < 2; ++p) {                           \
      _Pragma("unroll") for (int i = 0; i < 4; ++i) {                         \
        const int row = (mq * 4 + i) * BT + p * 8 + bq;                       \
        const unsigned v = pack2(ELEM(ST[p], i) - ELEM(mvE, i),               \
                                 ELEM(ST[2 + p], i) - ELEM(mvO, i));          \
        *(unsigned*)((XW) + row * 128 + xsw(row, chunkS) * 16 + (u & 3) * 4)  \
            = v;                                                              \
      }                                                                       \
    }                                                                         \
  }

#define BAR()                                          \
  {                                                    \
    asm volatile("s_waitcnt lgkmcnt(0)" ::: "memory"); \
    __builtin_amdgcn_s_barrier();                      \
  }

  // ---- prologue ----
  ISSUE(st0, 0)
  ISSUE(st1, 1)
  const float4 mvE = *(const float4*)(mean + (size_t)d2 * Mm + m0 + mq * 4);
  const float4 mvO =
      *(const float4*)(mean + (size_t)(d2 + 1) * Mm + m0 + mq * 4);

  short8 A[4][2];
#pragma unroll
  for (int ct = 0; ct < 4; ++ct) {
#pragma unroll
    for (int ks = 0; ks < 2; ++ks) {
      const float* sp = S + ((size_t)(m0 + w) * Cc + ct * 16 + (l & 15)) * Cc +
                        ks * 32 + (l >> 4) * 8;
      const float4 f0 = *(const float4*)sp;
      const float4 f1 = *(const float4*)(sp + 4);
      short8 a;
      a[0] = bfc(f0.x); a[1] = bfc(f0.y); a[2] = bfc(f0.z); a[3] = bfc(f0.w);
      a[4] = bfc(f1.x); a[5] = bfc(f1.y); a[6] = bfc(f1.z); a[7] = bfc(f1.w);
      A[ct][ks] = a;
    }
  }
  STAGE(st0, xb0)
  BAR()

  // ZW: wave w owns m-slice w. vcol = (r ^ h ^ (w>>2)) & 3 -> 2-way banks.
#define ZW()                                                                  \
  {                                                                           \
    const int h = l >> 4;                                                     \
    _Pragma("unroll") for (int ct = 0; ct < 4; ++ct) {                        \
      _Pragma("unroll") for (int r = 0; r < 4; ++r) {                         \
        const int vcol = (r ^ h ^ (w >> 2)) & 3;                              \
        zl[w * 1024 + ct * 256 + h * 64 + vcol * 16 + (l & 15)] =             \
            acc[ct][r];                                                       \
      }                                                                       \
    }                                                                         \
  }

  // ZR: thread (mqr, br, clow); 4 c's (t2), each float4-over-m via 4 b32.
#define ZR(T)                                                                 \
  {                                                                           \
    _Pragma("unroll") for (int t2 = 0; t2 < 4; ++t2) {                        \
      const int c_ = t2 * 16 + clow;                                          \
      const int h = (c_ >> 2) & 3, r = c_ & 3;                                \
      const int vcol = (r ^ h ^ mqr) & 3;                                     \
      float v[4];                                                             \
      _Pragma("unroll") for (int i = 0; i < 4; ++i)                           \
          v[i] = zl[(mqr * 4 + i) * 1024 + t2 * 256 + h * 64 + vcol * 16 +    \
                    br];                                                      \
      *(float4*)(out + (size_t)((b0 + (T)*BT + br) * Cc + c_) * Mm + m0 +     \
                 mqr * 4) = make_float4(v[0], v[1], v[2], v[3]);              \
    }                                                                         \
  }

#define ITER(T, XR, XW, STC, STN)                                              \
  {                                                                            \
    const int rowB = w * BT + (l & 15);                                        \
    const short8 Bf0 = *(const short8*)(                                       \
        (XR) + rowB * 128 + xsw(rowB, (l >> 4)) * 16);                         \
    const short8 Bf1 = *(const short8*)(                                       \
        (XR) + rowB * 128 + xsw(rowB, 4 + (l >> 4)) * 16);                     \
    if ((T) + 2 < NB) ISSUE(STN, (T) + 2)                                      \
    f32x4 acc[4];                                                              \
    _Pragma("unroll") for (int ct = 0; ct < 4; ++ct) acc[ct] =                 \
        (f32x4){0.f, 0.f, 0.f, 0.f};                                           \
    _Pragma("unroll") for (int ct = 0; ct < 4; ++ct) acc[ct] =                 \
        __builtin_amdgcn_mfma_f32_16x16x32_bf16(A[ct][0], Bf0, acc[ct], 0, 0,  \
                                                0);                            \
    _Pragma("unroll") for (int ct = 0; ct < 4; ++ct) acc[ct] =                 \
        __builtin_amdgcn_mfma_f32_16x16x32_bf16(A[ct][1], Bf1, acc[ct], 0, 0,  \
                                                0);                            \
    if ((T) + 1 < NB) STAGE(STC, XW)                                           \
    BAR() /* x(T+1) staged, Bf(T) read, prev ZR done */                        \
    ZW()                                                                       \
    BAR() /* z visible */                                                      \
    ZR(T)                                                                      \
  }

  ITER(0, xb0, xb1, st1, st0)
  ITER(1, xb1, xb0, st0, st1)
  ITER(2, xb0, xb1, st1, st0)
  ITER(3, xb1, xb0, st0, st1)
  ITER(4, xb0, xb1, st1, st0)
  ITER(5, xb1, xb0, st0, st1)
  ITER(6, xb0, xb1, st1, st0)
  ITER(7, xb1, xb0, st0, st1)

#undef ITER
#undef ZR
#undef ZW
#undef BAR
#undef STAGE
#undef ISSUE
}

extern "C" void kernel_launch(void* const* d_in, const int* in_sizes, int n_in,
                              void* d_out, int out_size, void* d_ws,
                              size_t ws_size, hipStream_t stream) {
  const float* x = (const float*)d_in[0];
  const float* mean = (const float*)d_in[1];
  const float* S = (const float*)d_in[2];
  float* out = (float*)d_out;
  const int nblocks = (Mm / MT) * (Bb / (BT * NB));  // 32 * 8 = 256
  hipLaunchKernelGGL(zca_v10, dim3(nblocks), dim3(1024), LDSB, stream, x,
                     mean, S, out);
}

// Round 14
// 67.123 us; speedup vs baseline: 3.3409x; 1.0977x over previous
//
#include <hip/hip_runtime.h>
#include <hip/hip_bf16.h>

// z[b,c,m] = sum_d S[m,c,d] * (x[b,d,m] - mean[d,m])
// B=1024, C=64, M=512. x:(B,C,M) f32, mean:(1,C,M), S:(M,C,C), out f32.
//
// v12 = v10 (1024 thr, 16 waves, 1 m/wave, BT=16, NB=8, grid 256, A-frags in
// regs once/block, reg-held depth-2 prefetch, x LDS dbuf, conflict-free z
// transpose) with RE-PAIRED phases:
//   [ISSUE -> Bf -> MFMA -> ZW]  BAR_A  [ZR + stores + STAGE]  BAR_B
// STAGE rides in the memory phase (x dbuf makes it barrier-free vs Bf), so
// cvt-VALU overlaps LDS reads + store issue. 2 lgkm-only barriers/iter.

typedef __attribute__((ext_vector_type(8))) short short8;
typedef __attribute__((ext_vector_type(4))) float f32x4;

namespace {
constexpr int Mm = 512, Cc = 64, Bb = 1024;
constexpr int MT = 16, BT = 16, NB = 8;
constexpr size_t LDSB = 65536 + 65536;  // x dbuf 2x32 KB + z 64 KB = 128 KB

__device__ __forceinline__ short bfc(float f) {  // f32 -> bf16 RNE (HW cvt)
  __hip_bfloat16 h = __float2bfloat16(f);
  union { __hip_bfloat16 b; short s; } u;
  u.b = h;
  return u.s;
}
__device__ __forceinline__ unsigned pack2(float a, float b) {
  return (unsigned)(unsigned short)bfc(a) |
         ((unsigned)(unsigned short)bfc(b) << 16);
}
// x-LDS chunk swizzle (audited 2-way max on both sides)
__device__ __forceinline__ int xsw(int row, int c) {
  return c ^ (row & 7) ^ (((row >> 6) & 3) << 1);
}
}  // namespace

#define ELEM(V, I) ((I) == 0 ? (V).x : (I) == 1 ? (V).y : (I) == 2 ? (V).z : (V).w)

__global__ __launch_bounds__(1024, 4) void zca_v12(
    const float* __restrict__ x, const float* __restrict__ mean,
    const float* __restrict__ S, float* __restrict__ out) {
  extern __shared__ unsigned char lds[];
  unsigned char* xb0 = lds;            // 32 KB bf16 x tile, buffer 0
  unsigned char* xb1 = lds + 32768;    // 32 KB buffer 1
  float* zl = (float*)(lds + 65536);   // 64 KB z tile [16 m][1024]

  const int tid = threadIdx.x;
  const int l = tid & 63;
  const int w = __builtin_amdgcn_readfirstlane(tid >> 6);  // 0..15 = m_local

  // bijective XCD swizzle: 256 blocks; per XCD 4 m-tiles x 8 b-groups
  const int id = blockIdx.x;
  const int sw = ((id & 7) << 5) + (id >> 3);
  const int m0 = (sw >> 3) * MT;
  const int b0 = (sw & 7) * (BT * NB);

  // staging coords: thread covers (d2,d2+1) x {bq, 8+bq} x 4 m
  const int mq = tid & 3;
  const int u = (tid >> 2) & 15;
  const int bq = w >> 1;
  const int d2 = ((w & 1) << 5) + (u << 1);
  const int chunkS = ((w & 1) << 2) + (u >> 2);
  // z-read coords: quad lanes = 4 m-quads of same (c,b)
  const int mqr = tid & 3;
  const int br = (tid >> 2) & 15;
  const int clow = (tid >> 6) & 15;  // == w

  float4 st0[4], st1[4];

#define ISSUE(ST, T)                                                          \
  {                                                                           \
    _Pragma("unroll") for (int dd = 0; dd < 2; ++dd)                          \
        _Pragma("unroll") for (int p = 0; p < 2; ++p)                         \
            ST[dd * 2 + p] = *(const float4*)(                                \
                x + (size_t)((b0 + (T)*BT + p * 8 + bq) * Cc + d2 + dd) * Mm  \
                  + m0 + mq * 4);                                             \
  }

#define STAGE(ST, XW)                                                         \
  {                                                                           \
    _Pragma("unroll") for (int p = 0; p < 2; ++p) {                           \
      _Pragma("unroll") for (int i = 0; i < 4; ++i) {                         \
        const int row = (mq * 4 + i) * BT + p * 8 + bq;                       \
        const unsigned v = pack2(ELEM(ST[p], i) - ELEM(mvE, i),               \
                                 ELEM(ST[2 + p], i) - ELEM(mvO, i));          \
        *(unsigned*)((XW) + row * 128 + xsw(row, chunkS) * 16 + (u & 3) * 4)  \
            = v;                                                              \
      }                                                                       \
    }                                                                         \
  }

#define BAR()                                          \
  {                                                    \
    asm volatile("s_waitcnt lgkmcnt(0)" ::: "memory"); \
    __builtin_amdgcn_s_barrier();                      \
  }

  // ---- prologue ----
  ISSUE(st0, 0)
  ISSUE(st1, 1)
  const float4 mvE = *(const float4*)(mean + (size_t)d2 * Mm + m0 + mq * 4);
  const float4 mvO =
      *(const float4*)(mean + (size_t)(d2 + 1) * Mm + m0 + mq * 4);

  short8 A[4][2];
#pragma unroll
  for (int ct = 0; ct < 4; ++ct) {
#pragma unroll
    for (int ks = 0; ks < 2; ++ks) {
      const float* sp = S + ((size_t)(m0 + w) * Cc + ct * 16 + (l & 15)) * Cc +
                        ks * 32 + (l >> 4) * 8;
      const float4 f0 = *(const float4*)sp;
      const float4 f1 = *(const float4*)(sp + 4);
      short8 a;
      a[0] = bfc(f0.x); a[1] = bfc(f0.y); a[2] = bfc(f0.z); a[3] = bfc(f0.w);
      a[4] = bfc(f1.x); a[5] = bfc(f1.y); a[6] = bfc(f1.z); a[7] = bfc(f1.w);
      A[ct][ks] = a;
    }
  }
  STAGE(st0, xb0)
  BAR()

  // ZW: wave w owns m-slice w. vcol = (r ^ h ^ (w>>2)) & 3 -> 2-way banks.
#define ZW()                                                                  \
  {                                                                           \
    const int h = l >> 4;                                                     \
    _Pragma("unroll") for (int ct = 0; ct < 4; ++ct) {                        \
      _Pragma("unroll") for (int r = 0; r < 4; ++r) {                         \
        const int vcol = (r ^ h ^ (w >> 2)) & 3;                              \
        zl[w * 1024 + ct * 256 + h * 64 + vcol * 16 + (l & 15)] =             \
            acc[ct][r];                                                       \
      }                                                                       \
    }                                                                         \
  }

  // ZR: thread (mqr, br, clow); 4 c's (t2), each float4-over-m via 4 b32.
#define ZR(T)                                                                 \
  {                                                                           \
    _Pragma("unroll") for (int t2 = 0; t2 < 4; ++t2) {                        \
      const int c_ = t2 * 16 + clow;                                          \
      const int h = (c_ >> 2) & 3, r = c_ & 3;                                \
      const int vcol = (r ^ h ^ mqr) & 3;                                     \
      float v[4];                                                             \
      _Pragma("unroll") for (int i = 0; i < 4; ++i)                           \
          v[i] = zl[(mqr * 4 + i) * 1024 + t2 * 256 + h * 64 + vcol * 16 +    \
                    br];                                                      \
      *(float4*)(out + (size_t)((b0 + (T)*BT + br) * Cc + c_) * Mm + m0 +     \
                 mqr * 4) = make_float4(v[0], v[1], v[2], v[3]);              \
    }                                                                         \
  }

  // Phases: [ISSUE, Bf, MFMA, ZW] BAR_A [ZR+stores, STAGE] BAR_B
#define ITER(T, XR, XW, STC, STN)                                              \
  {                                                                            \
    if ((T) + 2 < NB) ISSUE(STN, (T) + 2)                                      \
    const int rowB = w * BT + (l & 15);                                        \
    const short8 Bf0 = *(const short8*)(                                       \
        (XR) + rowB * 128 + xsw(rowB, (l >> 4)) * 16);                         \
    const short8 Bf1 = *(const short8*)(                                       \
        (XR) + rowB * 128 + xsw(rowB, 4 + (l >> 4)) * 16);                     \
    f32x4 acc[4];                                                              \
    _Pragma("unroll") for (int ct = 0; ct < 4; ++ct) acc[ct] =                 \
        (f32x4){0.f, 0.f, 0.f, 0.f};                                           \
    _Pragma("unroll") for (int ct = 0; ct < 4; ++ct) acc[ct] =                 \
        __builtin_amdgcn_mfma_f32_16x16x32_bf16(A[ct][0], Bf0, acc[ct], 0, 0,  \
                                                0);                            \
    _Pragma("unroll") for (int ct = 0; ct < 4; ++ct) acc[ct] =                 \
        __builtin_amdgcn_mfma_f32_16x16x32_bf16(A[ct][1], Bf1, acc[ct], 0, 0,  \
                                                0);                            \
    ZW()                                                                       \
    BAR() /* A: z visible; Bf(T) reads done (prev ZR done via prior BAR_B) */  \
    ZR(T)                                                                      \
    if ((T) + 1 < NB) STAGE(STC, XW)                                           \
    if ((T) + 1 < NB) BAR() /* B: x staged + ZR reads done before next ZW */   \
  }

  ITER(0, xb0, xb1, st1, st0)
  ITER(1, xb1, xb0, st0, st1)
  ITER(2, xb0, xb1, st1, st0)
  ITER(3, xb1, xb0, st0, st1)
  ITER(4, xb0, xb1, st1, st0)
  ITER(5, xb1, xb0, st0, st1)
  ITER(6, xb0, xb1, st1, st0)
  ITER(7, xb1, xb0, st0, st1)

#undef ITER
#undef ZR
#undef ZW
#undef BAR
#undef STAGE
#undef ISSUE
}

extern "C" void kernel_launch(void* const* d_in, const int* in_sizes, int n_in,
                              void* d_out, int out_size, void* d_ws,
                              size_t ws_size, hipStream_t stream) {
  const float* x = (const float*)d_in[0];
  const float* mean = (const float*)d_in[1];
  const float* S = (const float*)d_in[2];
  float* out = (float*)d_out;
  const int nblocks = (Mm / MT) * (Bb / (BT * NB));  // 32 * 8 = 256
  hipLaunchKernelGGL(zca_v12, dim3(nblocks), dim3(1024), LDSB, stream, x,
                     mean, S, out);
}